// Round 1
// baseline (340.863 us; speedup 1.0000x reference)
//
#include <hip/hip_runtime.h>

// Problem constants (from reference):
//   B=64, S=128, T=16, E_ELMO=1024, D_TRI=100, out dim = 1124 (f32)
constexpr int Bc = 64;
constexpr int Sc = 128;
constexpr int Tc = 16;
constexpr int Ec = 1024;   // token embedding dim
constexpr int Dc = 100;    // entity embedding dim
constexpr int OUTD = Ec + Dc;  // 1124

__global__ __launch_bounds__(256) void triple_fuse_kernel(
    const int*   __restrict__ inputs,   // [B*S]
    const int*   __restrict__ triples,  // [B*S*T*3]
    const int*   __restrict__ id2,      // [B*S*T]
    const float* __restrict__ emb,      // [VOCAB*E]
    const float* __restrict__ ent,      // [ENT_VOCAB*D]
    float*       __restrict__ out)      // [B*S*OUTD]
{
    const int token = blockIdx.x;       // one block per token, grid = B*S
    const int tid   = threadIdx.x;

    __shared__ int s_idx[Tc];           // entity row per slot, -1 if invalid

    if (tid < Tc) {
        const int slot = token * Tc + tid;
        const int flag = id2[slot];
        const int tri0 = triples[slot * 3 + 0];
        const int tri1 = triples[slot * 3 + 1];
        int e = -1;
        if (flag == 1) e = tri1;        // tail entity
        else if (flag == 2) e = tri0;   // head entity
        s_idx[tid] = e;
    }
    __syncthreads();

    // --- token-embedding copy: 256 threads x float4 = 1024 floats ---
    // out row byte stride = 1124*4 = 4496 = 16*281 -> float4 stores stay aligned.
    const long trow = (long)inputs[token] * Ec;
    const float4 v = ((const float4*)(emb + trow))[tid];
    ((float4*)(out + (long)token * OUTD))[tid] = v;

    // --- entity average: threads 0..99 each own one dim d ---
    if (tid < Dc) {
        float sum = 0.f;
        int   cnt = 0;
        #pragma unroll
        for (int j = 0; j < Tc; ++j) {
            const int e = s_idx[j];     // wave-uniform branch (shared value)
            if (e >= 0) {
                sum += ent[(long)e * Dc + tid];
                ++cnt;
            }
        }
        const float avg = (cnt > 0) ? sum / (float)cnt : 0.f;
        out[(long)token * OUTD + Ec + tid] = avg;
    }
}

extern "C" void kernel_launch(void* const* d_in, const int* in_sizes, int n_in,
                              void* d_out, int out_size, void* d_ws, size_t ws_size,
                              hipStream_t stream) {
    const int*   inputs  = (const int*)d_in[0];
    const int*   triples = (const int*)d_in[1];
    const int*   id2     = (const int*)d_in[2];
    const float* emb     = (const float*)d_in[3];
    const float* ent     = (const float*)d_in[4];
    float*       out     = (float*)d_out;

    const int n_tokens = Bc * Sc;  // 8192
    triple_fuse_kernel<<<n_tokens, 256, 0, stream>>>(inputs, triples, id2, emb, ent, out);
}

// Round 2
// 331.273 us; speedup vs baseline: 1.0289x; 1.0289x over previous
//
#include <hip/hip_runtime.h>

// Problem constants (from reference):
//   B=64, S=128, T=16, E_ELMO=1024, D_TRI=100, out row = 1124 f32
constexpr int Bc = 64;
constexpr int Sc = 128;
constexpr int Tc = 16;
constexpr int Ec = 1024;       // token embedding dim
constexpr int Dc = 100;        // entity embedding dim (= 25 float4, 400 B, 16B-aligned rows)
constexpr int OUTD = Ec + Dc;  // 1124

__global__ __launch_bounds__(256) void triple_fuse_kernel(
    const int*   __restrict__ inputs,   // [B*S]
    const int*   __restrict__ triples,  // [B*S*T*3]
    const int*   __restrict__ id2,      // [B*S*T]
    const float* __restrict__ emb,      // [VOCAB*E]
    const float* __restrict__ ent,      // [ENT_VOCAB*D]
    float*       __restrict__ out)      // [B*S*OUTD]
{
    const int token = blockIdx.x;       // one block per token, grid = B*S
    const int tid   = threadIdx.x;

    __shared__ int   s_idx[Tc];         // compacted valid entity rows
    __shared__ int   s_cnt;
    __shared__ float s_g[Tc * Dc];      // 6.4 KB staging: [slot][dim]

    // --- issue the token-embedding load early (independent of everything) ---
    const long trow = (long)inputs[token] * Ec;
    const float4 tv = ((const float4*)(emb + trow))[tid];

    // --- decode flags -> entity index, compact valid ones via wave-0 ballot ---
    int e = -1;
    if (tid < Tc) {
        const int slot = token * Tc + tid;
        const int flag = id2[slot];
        if (flag == 1)      e = triples[slot * 3 + 1];  // tail entity
        else if (flag == 2) e = triples[slot * 3 + 0];  // head entity
    }
    if (tid < 64) {  // exactly wave 0; lanes 16..63 contribute 0 to the ballot
        const unsigned long long m = __ballot(e >= 0);
        if (e >= 0) {
            const int pos = __popcll(m & ((1ull << tid) - 1ull));
            s_idx[pos] = e;
        }
        if (tid == 0) s_cnt = (int)__popcll(m);
    }
    __syncthreads();
    const int cnt = s_cnt;

    // --- store token part (write after barrier; load was issued early) ---
    ((float4*)(out + (long)token * OUTD))[tid] = tv;

    // --- entity gather: cnt*25 independent aligned float4 loads across 256 threads ---
    const int total = cnt * 25;                  // float4s to fetch (<= 400)
    for (int i = tid; i < total; i += 256) {
        const int j = i / 25;                    // slot
        const int p = i - j * 25;                // float4 position in row
        const float4 g = ((const float4*)(ent + (long)s_idx[j] * Dc))[p];
        ((float4*)s_g)[i] = g;                   // s_g[j*100 + 4p ...], i = j*25+p
    }
    __syncthreads();

    // --- reduce over slots, average, store (conflict-free LDS reads) ---
    if (tid < Dc) {
        float sum = 0.f;
        for (int j = 0; j < cnt; ++j) sum += s_g[j * Dc + tid];
        out[(long)token * OUTD + Ec + tid] = (cnt > 0) ? sum / (float)cnt : 0.f;
    }
}

extern "C" void kernel_launch(void* const* d_in, const int* in_sizes, int n_in,
                              void* d_out, int out_size, void* d_ws, size_t ws_size,
                              hipStream_t stream) {
    const int*   inputs  = (const int*)d_in[0];
    const int*   triples = (const int*)d_in[1];
    const int*   id2     = (const int*)d_in[2];
    const float* emb     = (const float*)d_in[3];
    const float* ent     = (const float*)d_in[4];
    float*       out     = (float*)d_out;

    triple_fuse_kernel<<<Bc * Sc, 256, 0, stream>>>(inputs, triples, id2, emb, ent, out);
}

// Round 3
// 330.026 us; speedup vs baseline: 1.0328x; 1.0038x over previous
//
#include <hip/hip_runtime.h>

// Problem constants (from reference):
//   B=64, S=128, T=16, E_ELMO=1024, D_TRI=100, out row = 1124 f32
constexpr int Bc = 64;
constexpr int Sc = 128;
constexpr int Tc = 16;
constexpr int Ec = 1024;       // token embedding dim (256 float4)
constexpr int Dc = 100;        // entity embedding dim (400 B rows, 16B-aligned)
constexpr int OUTD = Ec + Dc;  // 1124 (row stride 4496 B, 16B-aligned)

__global__ __launch_bounds__(256) void triple_fuse_kernel(
    const int*   __restrict__ inputs,   // [B*S]
    const int*   __restrict__ triples,  // [B*S*T*3]
    const int*   __restrict__ id2,      // [B*S*T]
    const float* __restrict__ emb,      // [VOCAB*E]
    const float* __restrict__ ent,      // [ENT_VOCAB*D]
    float*       __restrict__ out)      // [B*S*OUTD]
{
    const int token = blockIdx.x;       // one block per token, grid = B*S
    const int tid   = threadIdx.x;

    __shared__ int s_idx[Tc];           // compacted valid entity rows, 0-padded
    __shared__ int s_cnt;

    // --- issue the (uniform-row) token-embedding load early ---
    const long trow = (long)inputs[token] * Ec;
    const float4 tv = ((const float4*)(emb + trow))[tid];

    // --- wave 0 only: decode flags -> entity idx, ballot-compact into s_idx ---
    if (tid < 64) {
        int e = -1;
        if (tid < Tc) {
            s_idx[tid] = 0;             // pad (same wave, program-order before compact write)
            const int slot = token * Tc + tid;
            const int flag = id2[slot];
            if (flag == 1)      e = triples[slot * 3 + 1];  // tail entity
            else if (flag == 2) e = triples[slot * 3 + 0];  // head entity
        }
        const unsigned long long m = __ballot(e >= 0);
        if (e >= 0) {
            const int pos = __popcll(m & ((1ull << tid) - 1ull));
            s_idx[pos] = e;
        }
        if (tid == 0) s_cnt = (int)__popcll(m);
    }
    __syncthreads();                    // single barrier

    // --- store token part (load already in flight before the barrier) ---
    ((float4*)(out + (long)token * OUTD))[tid] = tv;

    // --- entity average: threads 0..99 accumulate in registers.
    //     Fixed 16-iter unrolled loop => all loads independent, one round-trip.
    //     Slots >= cnt read row s_idx[j]==0 (L2-hot) and are masked out. ---
    if (tid < Dc) {
        const int cnt = s_cnt;          // wave-uniform
        float sum = 0.f;
        #pragma unroll
        for (int j = 0; j < Tc; ++j) {
            const float v = ent[(long)s_idx[j] * Dc + tid];  // always-safe address
            sum += (j < cnt) ? v : 0.f;
        }
        out[(long)token * OUTD + Ec + tid] = (cnt > 0) ? sum / (float)cnt : 0.f;
    }
}

extern "C" void kernel_launch(void* const* d_in, const int* in_sizes, int n_in,
                              void* d_out, int out_size, void* d_ws, size_t ws_size,
                              hipStream_t stream) {
    const int*   inputs  = (const int*)d_in[0];
    const int*   triples = (const int*)d_in[1];
    const int*   id2     = (const int*)d_in[2];
    const float* emb     = (const float*)d_in[3];
    const float* ent     = (const float*)d_in[4];
    float*       out     = (float*)d_out;

    triple_fuse_kernel<<<Bc * Sc, 256, 0, stream>>>(inputs, triples, id2, emb, ent, out);
}